// Round 11
// baseline (869.073 us; speedup 1.0000x reference)
//
#include <hip/hip_runtime.h>

#define BETA 0.96f
#define NB 4096
#define NI 96
#define NH 50
#define NO 2
#define NT 250
#define HP 26                  // padded half-width: floats per row per half-table
#define WTBL (NI * HP)         // 2496 floats = 9.98 KB per half-table (< 16 KB K$)

// Split W1 into two packed transposed half-tables (each K$-resident):
//   w1a[i*HP + j] = W1[j][i]        (h = 0..25)
//   w1b[i*HP + j] = W1[26+j][i]     (h = 26..49; j = 24,25 zero-pad)
__global__ void w1_split_kernel(const float* __restrict__ W1,
                                float* __restrict__ w1a,
                                float* __restrict__ w1b) {
    int idx = blockIdx.x * blockDim.x + threadIdx.x;
    if (idx >= WTBL) return;
    int i = idx / HP;
    int j = idx - i * HP;
    w1a[idx] = W1[j * NI + i];
    w1b[idx] = (26 + j < NH) ? W1[(26 + j) * NI + i] : 0.0f;
}

// One half-GEMM pass: acc[j] = sum_i x[i][my_t] * WT[i][j], j = 0..25.
// WT rows are wave-uniform -> scalar K$ loads (free operand at VALU issue).
// x loads ride an 8-deep per-lane ring (coalesced, HBM-latency covering).
#define GEMM_HALF(WT)                                                     \
    {                                                                     \
        _Pragma("unroll")                                                 \
        for (int j = 0; j < HP; ++j) acc[j] = 0.0f;                       \
        float xa[8], xc[8];                                               \
        _Pragma("unroll")                                                 \
        for (int g = 0; g < 8; ++g) xa[g] = xb[g * NT];                   \
        _Pragma("unroll 1")                                               \
        for (int blk = 0; blk < 12; blk += 2) {                           \
            const int ib0 = blk * 8;                                      \
            _Pragma("unroll")                                             \
            for (int g = 0; g < 8; ++g) xc[g] = xb[(ib0 + 8 + g) * NT];   \
            _Pragma("unroll")                                             \
            for (int g = 0; g < 8; ++g) {                                 \
                const float* wr = (WT) + (ib0 + g) * HP;                  \
                const float xv = xa[g];                                   \
                _Pragma("unroll")                                         \
                for (int j = 0; j < HP; ++j)                              \
                    acc[j] = fmaf(xv, wr[j], acc[j]);                     \
            }                                                             \
            _Pragma("unroll")                                             \
            for (int g = 0; g < 8; ++g) {                                 \
                int inx = ib0 + 16 + g; if (inx > NI - 1) inx = NI - 1;   \
                xa[g] = xb[inx * NT];                                     \
            }                                                             \
            _Pragma("unroll")                                             \
            for (int g = 0; g < 8; ++g) {                                 \
                const float* wr = (WT) + (ib0 + 8 + g) * HP;              \
                const float xv = xc[g];                                   \
                _Pragma("unroll")                                         \
                for (int j = 0; j < HP; ++j)                              \
                    acc[j] = fmaf(xv, wr[j], acc[j]);                     \
            }                                                             \
        }                                                                 \
    }

// Workgroup = 8 waves = 8 batch elements, EXACTLY one workgroup per CU
// (LDS 108 KB blocks a second). Barriers keep all 8 waves in the SAME
// W1 half-table so the CU-wide scalar working set is 9.98 KB -> K$ hits.
// Phase A (lanes = t): half-GEMMs, x per-lane coalesced (half 2 re-read is L2-hot).
// Phase B (lanes = h): serial LIF via per-wave LDS bounce; ballot -> masks.
// Phase C (lanes = t): mask-dot W2 + Kogge-Stone beta-weighted scan.
__global__ __launch_bounds__(512, 2) void snn_fused_kernel(
    const float* __restrict__ x,
    const float* __restrict__ w1a,
    const float* __restrict__ w1b,
    const float* __restrict__ W2,
    float* __restrict__ out)
{
    __shared__ float cur1[8][52][65];      // 108,160 B: [wave][h][t], pad -> 2-way
    const int wid  = threadIdx.x >> 6;
    const int lane = threadIdx.x & 63;
    const int b = (blockIdx.x << 3) + wid;

    float mem1 = 0.0f;                     // lane = h state, persists over chunks
    float m2a = 0.0f, m2b = 0.0f;          // mem2 carry
    const float bpow = exp2f((float)(lane + 1) * -0.05889368905356867f); // beta^(lane+1)
    const int hcl = (lane < NH) ? lane : (NH - 1);

    const float* xrow_base = x + (size_t)b * (NI * NT);

    #pragma unroll 1
    for (int c = 0; c < 4; ++c) {
        const int t0 = c * 64;
        const int TT = (NT - t0 < 64) ? (NT - t0) : 64;           // 64,64,64,58
        const int tl = (t0 + lane < NT) ? (t0 + lane) : (NT - 1); // clamped t
        const float* xb = xrow_base + tl;

        float acc[HP];

        // ---------------- Phase A, half 0: h = 0..25 ----------------
        GEMM_HALF(w1a)
        #pragma unroll
        for (int j = 0; j < HP; ++j) cur1[wid][j][lane] = acc[j];
        __syncthreads();   // all waves leave w1a together (K$ residency)

        // ---------------- Phase A, half 1: h = 26..49 ----------------
        GEMM_HALF(w1b)
        #pragma unroll
        for (int j = 0; j < 24; ++j) cur1[wid][26 + j][lane] = acc[j];

        // ---------------- Phase B: serial LIF, lanes = h (per-wave) ----------
        unsigned vml = 0u, vmh = 0u;       // spike masks redistributed to lane=t
        for (int t = 0; t < TT; ++t) {
            const float cur = cur1[wid][hcl][t];
            const float base = fmaf(BETA, mem1, cur);
            mem1 = (mem1 > 1.0f) ? 0.0f : base;      // reset='zero'
            const unsigned long long m = __ballot(mem1 > 1.0f);
            const unsigned lo = (unsigned)(m & 0xffffffffull);
            const unsigned hi = (unsigned)(m >> 32);
            const bool mine = (lane == t);
            vml = mine ? lo : vml;
            vmh = mine ? hi : vmh;
        }

        // ---------------- Phase C: cur2 + mem2 scan, lanes = t ----------------
        float c2a = 0.0f, c2b = 0.0f;
        #pragma unroll
        for (int h = 0; h < NH; ++h) {
            const unsigned w = (h < 32) ? vml : vmh;
            const float bit = (float)((w >> (h & 31)) & 1u);
            c2a = fmaf(bit, W2[h], c2a);             // W2[0][h]
            c2b = fmaf(bit, W2[NH + h], c2b);        // W2[1][h]
        }
        float sa = c2a, sb = c2b;
        float bk = BETA;
        #pragma unroll
        for (int k = 1; k <= 32; k <<= 1) {
            const float pa = __shfl_up(sa, (unsigned)k, 64);
            const float pb = __shfl_up(sb, (unsigned)k, 64);
            if (lane >= k) {
                sa = fmaf(bk, pa, sa);
                sb = fmaf(bk, pb, sb);
            }
            bk *= bk;
        }
        const float outa = fmaf(bpow, m2a, sa);      // + beta^(lane+1) * carry
        const float outb = fmaf(bpow, m2b, sb);
        m2a = __shfl(outa, TT - 1, 64);
        m2b = __shfl(outb, TT - 1, 64);
        if (lane < TT) {
            out[((size_t)b * NO + 0) * NT + t0 + lane] = outa;
            out[((size_t)b * NO + 1) * NT + t0 + lane] = outb;
        }
        __syncthreads();   // re-converge waves before next chunk's w1a pass
    }
}

extern "C" void kernel_launch(void* const* d_in, const int* in_sizes, int n_in,
                              void* d_out, int out_size, void* d_ws, size_t ws_size,
                              hipStream_t stream) {
    const float* x  = (const float*)d_in[0];
    const float* W1 = (const float*)d_in[1];
    const float* W2 = (const float*)d_in[2];
    float* out = (float*)d_out;
    float* w1a = (float*)d_ws;                 // WTBL floats
    float* w1b = (float*)d_ws + WTBL;          // WTBL floats (20 KB total scratch)

    hipLaunchKernelGGL(w1_split_kernel, dim3((WTBL + 255) / 256),
                       dim3(256), 0, stream, W1, w1a, w1b);
    hipLaunchKernelGGL(snn_fused_kernel, dim3(NB / 8), dim3(512), 0, stream,
                       x, w1a, w1b, W2, out);
}